// Round 6
// baseline (268.925 us; speedup 1.0000x reference)
//
#include <hip/hip_runtime.h>
#include <hip/hip_bf16.h>

#define B_   4
#define T_   1024
#define DM   2048
#define QKVD 3072   // 64*(32+16)

typedef __attribute__((ext_vector_type(8))) short bf16x8;
typedef __attribute__((ext_vector_type(4))) short short4v;
typedef __attribute__((ext_vector_type(4))) float f32x4;

__device__ __forceinline__ void load_lds16(const void* g, void* l) {
  __builtin_amdgcn_global_load_lds((const __attribute__((address_space(1))) void*)g,
                                   (__attribute__((address_space(3))) void*)l, 16, 0, 0);
}

__device__ __forceinline__ short f2bf(float f) {
  __hip_bfloat16 h = __float2bfloat16(f);
  return *reinterpret_cast<short*>(&h);
}

// Fused fp32 -> bf16 convert for x (8.4M), qkv_w (6.3M), out_w (4.2M).
__global__ __launch_bounds__(256) void cvt_kernel(const float* __restrict__ x,
                                                  const float* __restrict__ w1,
                                                  const float* __restrict__ w2,
                                                  short* __restrict__ xo,
                                                  short* __restrict__ w1o,
                                                  short* __restrict__ w2o) {
  unsigned c = blockIdx.x * 256u + threadIdx.x;  // 0 .. 4718591
  const float* src;
  short* dst;
  if (c < 2097152u) {                 // x
    src = x; dst = xo;
  } else if (c < 3670016u) {          // qkv_w
    c -= 2097152u; src = w1; dst = w1o;
  } else {                            // out_w
    c -= 3670016u; src = w2; dst = w2o;
  }
  const float4 v = ((const float4*)src)[c];
  short4v o;
  o.x = f2bf(v.x); o.y = f2bf(v.y); o.z = f2bf(v.z); o.w = f2bf(v.w);
  ((short4v*)dst)[c] = o;
}

// Shared GEMM K-loop: m97 structure, BK=64 (32 MFMAs per barrier-pair — halves
// the vmcnt(0)+s_barrier drain count vs BK=32), 3-bit XOR bank swizzle
// (LDS chunk (r,qc) holds global chunk qc^(r&7); frag b128 reads then spread
// 2-way over all 32 banks = free per m136). K fixed at 2048. LDS 32 KB/block
// (occupancy is grid-limited at 2-3 blocks/CU, so no occupancy loss).
#define GEMM_PROLOGUE_AND_KLOOP(A_, B_ptr)                                         \
  __shared__ short As[128 * 64];                                                   \
  __shared__ short Bs[128 * 64];                                                   \
  const int tid  = threadIdx.x;                                                    \
  const int lane = tid & 63;                                                       \
  const int wave = tid >> 6;                                                       \
  const int wm = wave >> 1, wn = wave & 1;                                         \
  const int r15 = lane & 15, quad = lane >> 4;                                     \
  const int m0 = blockIdx.y * 128, n0 = blockIdx.x * 128;                          \
  f32x4 acc[4][4];                                                                 \
  _Pragma("unroll") for (int i = 0; i < 4; ++i)                                    \
    _Pragma("unroll") for (int j = 0; j < 4; ++j) acc[i][j] = {0.f,0.f,0.f,0.f};   \
  const short* gA[4]; const short* gB[4]; short* lA[4]; short* lB[4];              \
  _Pragma("unroll") for (int i = 0; i < 4; ++i) {                                  \
    const int c = i * 256 + tid;                                                   \
    const int r = c >> 3, qs = (c & 7) ^ (r & 7);                                  \
    gA[i] = A_ + (size_t)(m0 + r) * 2048 + qs * 8;                                 \
    gB[i] = B_ptr + (size_t)(n0 + r) * 2048 + qs * 8;                              \
    lA[i] = &As[c * 8];                                                            \
    lB[i] = &Bs[c * 8];                                                            \
  }                                                                                \
  const int swf = r15 & 7;                                                         \
  for (int k0 = 0; k0 < 2048; k0 += 64) {                                          \
    __syncthreads();                                                               \
    _Pragma("unroll") for (int i = 0; i < 4; ++i) {                                \
      load_lds16(gA[i], lA[i]);                                                    \
      load_lds16(gB[i], lB[i]);                                                    \
      gA[i] += 64; gB[i] += 64;                                                    \
    }                                                                              \
    __syncthreads();                                                               \
    _Pragma("unroll") for (int kc = 0; kc < 2; ++kc) {                             \
      bf16x8 af[4], bfr[4];                                                        \
      _Pragma("unroll") for (int tm = 0; tm < 4; ++tm)                             \
        af[tm] = *(const bf16x8*)&As[(wm*64+tm*16+r15)*64 + ((kc*4+quad)^swf)*8];  \
      _Pragma("unroll") for (int tn = 0; tn < 4; ++tn)                             \
        bfr[tn] = *(const bf16x8*)&Bs[(wn*64+tn*16+r15)*64 + ((kc*4+quad)^swf)*8]; \
      _Pragma("unroll") for (int tm = 0; tm < 4; ++tm)                             \
        _Pragma("unroll") for (int tn = 0; tn < 4; ++tn)                           \
          acc[tm][tn] = __builtin_amdgcn_mfma_f32_16x16x32_bf16(af[tm], bfr[tn],   \
                                                            acc[tm][tn], 0, 0, 0); \
    }                                                                              \
  }

// QKV projection with fused bias + YaRN RoPE + SM_SCALE; q/k -> bf16 qkvb,
// v -> bf16 vT[b][kv][d][t] (transposed for attention's PV B-frags).
__global__ __launch_bounds__(256) void gemm_qkv(const short* __restrict__ A,
                                                const short* __restrict__ Bw,
                                                const float* __restrict__ bias,
                                                short* __restrict__ qkvb,
                                                short* __restrict__ vT) {
  GEMM_PROLOGUE_AND_KLOOP(A, Bw)

  if (blockIdx.x < 20) {
    // q (cols<2048) or k (2048..2559): bias + rope (+0.125 scale for q)
    const float scale = (blockIdx.x < 16) ? 0.125f : 1.0f;
    float invf[2];
#pragma unroll
    for (int tnh = 0; tnh < 2; ++tnh) {
      const float fi = (float)(tnh * 16 + r15);   // i = col & 31
      const float freq = __powf(150000.f, fi * (1.f / 32.f));
      float ramp = (fi - 4.3707300f) * (1.f / 9.3052397f);
      ramp = fminf(fmaxf(ramp, 0.f), 1.f);
      invf[tnh] = ramp / (32.f * freq) + (1.f - ramp) / freq;
    }
    float bv[4];
#pragma unroll
    for (int tn = 0; tn < 4; ++tn) bv[tn] = bias[n0 + wn * 64 + tn * 16 + r15];
#pragma unroll
    for (int tm = 0; tm < 4; ++tm)
#pragma unroll
      for (int v = 0; v < 4; ++v) {
        const int row = m0 + wm * 64 + tm * 16 + quad * 4 + v;
        const float ft = (float)(row & 1023);       // per-batch position
#pragma unroll
        for (int tnh = 0; tnh < 2; ++tnh) {
          const float ph = ft * invf[tnh];
          const float c = __cosf(ph) * 1.3465736f;  // concentration = 0.1*ln(32)+1
          const float s = __sinf(ph) * 1.3465736f;
          const float x1 = acc[tm][tnh][v] + bv[tnh];
          const float x2 = acc[tm][tnh + 2][v] + bv[tnh + 2];
          short* qp = qkvb + (size_t)row * QKVD + (n0 + wn * 64 + tnh * 16 + r15);
          qp[0]  = f2bf((x1 * c - x2 * s) * scale);
          qp[32] = f2bf((x2 * c + x1 * s) * scale);
        }
      }
  } else {
    // v (cols 2560..3071): bias, write transposed vT[b][kv][d][t], short4 packs
#pragma unroll
    for (int tn = 0; tn < 4; ++tn) {
      const int col = n0 + wn * 64 + tn * 16 + r15;
      const float bvv = bias[col];
      const int d = col & 63;
      const int kvh = (col - 2560) >> 6;
#pragma unroll
      for (int tm = 0; tm < 4; ++tm) {
        const int row = m0 + wm * 64 + tm * 16 + quad * 4;
        const int bb = row >> 10, tt = row & 1023;
        short4v st;
        st.x = f2bf(acc[tm][tn][0] + bvv);
        st.y = f2bf(acc[tm][tn][1] + bvv);
        st.z = f2bf(acc[tm][tn][2] + bvv);
        st.w = f2bf(acc[tm][tn][3] + bvv);
        *(short4v*)&vT[(size_t)((bb * 8 + kvh) * 64 + d) * 1024 + tt] = st;
      }
    }
  }
}

// Output projection: C fp32 = A bf16 * B^T bf16 + bias
__global__ __launch_bounds__(256) void gemm_out(const short* __restrict__ A,
                                                const short* __restrict__ Bw,
                                                const float* __restrict__ bias,
                                                float* __restrict__ C) {
  GEMM_PROLOGUE_AND_KLOOP(A, Bw)
#pragma unroll
  for (int tn = 0; tn < 4; ++tn) {
    const int col = n0 + wn * 64 + tn * 16 + r15;
    const float bv = bias[col];
#pragma unroll
    for (int tm = 0; tm < 4; ++tm) {
      const int row = m0 + wm * 64 + tm * 16 + quad * 4;
#pragma unroll
      for (int v = 0; v < 4; ++v)
        C[(size_t)(row + v) * DM + col] = acc[tm][tn][v] + bv;
    }
  }
}

// MFMA flash-style sliding-window attention, all-bf16 inputs.
// Block = (b, kv, 32-query tile), 4 waves = 4 GQA sub-heads, 4 blocks/CU.
// K/V staged via global_load_lds (16B) into unpadded 64-stride LDS with the
// same 3-bit XOR swizzle as the GEMMs (2-way banks = free). P per-wave in LDS
// padded to stride 72 (VALU-written). Fixed m=0 softmax (exact: shift-invariant,
// scores bounded well below exp overflow).
#define LSTR 72
__global__ __launch_bounds__(256, 4) void attn_kernel(const short* __restrict__ qkvb,
                                                      const short* __restrict__ vT,
                                                      const float* __restrict__ sinks,
                                                      short* __restrict__ attn_out) {
  __shared__ short Kb[64 * 64];        // [key][dim], swizzled chunks
  __shared__ short Vt[64 * 64];        // [dim][key], swizzled chunks
  __shared__ short Pl[4][32 * LSTR];   // per-wave [query][key]
  const int tid  = threadIdx.x;
  const int lane = tid & 63;
  const int m    = tid >> 6;
  const int r15  = lane & 15, quad = lane >> 4;
  const int t0 = blockIdx.x * 32;
  const int kv = blockIdx.y;
  const int b  = blockIdx.z;
  const int swf = r15 & 7;

  bf16x8 qf[2][2];
#pragma unroll
  for (int tm = 0; tm < 2; ++tm)
#pragma unroll
    for (int kc = 0; kc < 2; ++kc)
      qf[tm][kc] = *(const bf16x8*)&qkvb[(size_t)(b * T_ + t0 + tm * 16 + r15) * QKVD
                                         + kv * 256 + m * 64 + kc * 32 + quad * 8];

  f32x4 oacc[2][4];
#pragma unroll
  for (int i = 0; i < 2; ++i)
#pragma unroll
    for (int j = 0; j < 4; ++j) oacc[i][j] = {0.f, 0.f, 0.f, 0.f};
  float lf[8];
#pragma unroll
  for (int i = 0; i < 8; ++i) lf[i] = 0.f;

  const short* kbase = qkvb + (size_t)b * T_ * QKVD + 2048 + kv * 64;
  const short* vbase = vT + (size_t)((b * 8 + kv) * 64) * 1024;

  // 64-aligned key tiles covering [max(0, t0-127), t0+31]
  const int jt_lo = (t0 >= 127) ? ((t0 - 127) >> 6) : 0;
  const int jt_hi = (t0 + 31) >> 6;

  for (int jt = jt_lo; jt <= jt_hi; ++jt) {
    const int j0 = jt * 64;
    __syncthreads();  // previous tile fully consumed
#pragma unroll
    for (int i = 0; i < 2; ++i) {
      const int c = i * 256 + tid;
      const int r = c >> 3, qs = (c & 7) ^ (r & 7);
      load_lds16(kbase + (size_t)(j0 + r) * QKVD + qs * 8, &Kb[c * 8]);
      load_lds16(vbase + (size_t)r * 1024 + j0 + qs * 8, &Vt[c * 8]);
    }
    __syncthreads();  // vmcnt(0) drain -> LDS ready

    // S = Q K^T : C/D layout col(key)=tn*16+r15, row(query)=tm*16+quad*4+v
    f32x4 sacc[2][4];
#pragma unroll
    for (int i = 0; i < 2; ++i)
#pragma unroll
      for (int j = 0; j < 4; ++j) sacc[i][j] = {0.f, 0.f, 0.f, 0.f};
#pragma unroll
    for (int kc = 0; kc < 2; ++kc) {
      bf16x8 bk[4];
#pragma unroll
      for (int tn = 0; tn < 4; ++tn)
        bk[tn] = *(const bf16x8*)&Kb[(tn * 16 + r15) * 64 + ((kc * 4 + quad) ^ swf) * 8];
#pragma unroll
      for (int tm = 0; tm < 2; ++tm)
#pragma unroll
        for (int tn = 0; tn < 4; ++tn)
          sacc[tm][tn] = __builtin_amdgcn_mfma_f32_16x16x32_bf16(qf[tm][kc], bk[tn],
                                                                 sacc[tm][tn], 0, 0, 0);
    }

    // mask + exp + row-sum partials + P to per-wave LDS
    short* pl = &Pl[m][0];
#pragma unroll
    for (int tm = 0; tm < 2; ++tm)
#pragma unroll
      for (int v = 0; v < 4; ++v) {
        const int ql = tm * 16 + quad * 4 + v;
        const int t = t0 + ql;
        float lsum = 0.f;
#pragma unroll
        for (int tn = 0; tn < 4; ++tn) {
          const int j = j0 + tn * 16 + r15;
          const bool valid = (unsigned)(t - j) <= 127u;
          const float e = valid ? __expf(sacc[tm][tn][v]) : 0.f;
          lsum += e;
          pl[ql * LSTR + tn * 16 + r15] = f2bf(e);
        }
        lf[tm * 4 + v] += lsum;
      }

    // O += P V (A from Pl, B from Vt; same-wave RAW via lgkmcnt)
#pragma unroll
    for (int kc = 0; kc < 2; ++kc) {
      bf16x8 ap[2], bv[4];
#pragma unroll
      for (int tm = 0; tm < 2; ++tm)
        ap[tm] = *(const bf16x8*)&pl[(tm * 16 + r15) * LSTR + kc * 32 + quad * 8];
#pragma unroll
      for (int tn = 0; tn < 4; ++tn)
        bv[tn] = *(const bf16x8*)&Vt[(tn * 16 + r15) * 64 + ((kc * 4 + quad) ^ swf) * 8];
#pragma unroll
      for (int tm = 0; tm < 2; ++tm)
#pragma unroll
        for (int tn = 0; tn < 4; ++tn)
          oacc[tm][tn] = __builtin_amdgcn_mfma_f32_16x16x32_bf16(ap[tm], bv[tn],
                                                                 oacc[tm][tn], 0, 0, 0);
    }
  }

  // reduce l over the 16-lane r15 group, fold sink, normalize, store bf16
#pragma unroll
  for (int i = 0; i < 8; ++i) {
    float v = lf[i];
    v += __shfl_xor(v, 1, 64);
    v += __shfl_xor(v, 2, 64);
    v += __shfl_xor(v, 4, 64);
    v += __shfl_xor(v, 8, 64);
    lf[i] = v;
  }
  const int h = kv * 4 + m;
  const float snk = __expf(sinks[h]);
#pragma unroll
  for (int tm = 0; tm < 2; ++tm)
#pragma unroll
    for (int v = 0; v < 4; ++v) {
      const float inv = 1.f / (lf[tm * 4 + v] + snk);
      const int t = t0 + tm * 16 + quad * 4 + v;
      short* op = attn_out + (size_t)(b * T_ + t) * DM + h * 64;
#pragma unroll
      for (int tn = 0; tn < 4; ++tn)
        op[tn * 16 + r15] = f2bf(oacc[tm][tn][v] * inv);
    }
}

extern "C" void kernel_launch(void* const* d_in, const int* in_sizes, int n_in,
                              void* d_out, int out_size, void* d_ws, size_t ws_size,
                              hipStream_t stream) {
  const float* x      = (const float*)d_in[0];   // fp32 (B,T,DM)
  const float* qkv_w  = (const float*)d_in[1];   // fp32 (3072,2048)
  const float* qkv_b  = (const float*)d_in[2];   // fp32 (3072,)
  const float* out_w  = (const float*)d_in[3];   // fp32 (2048,2048)
  const float* out_b  = (const float*)d_in[4];   // fp32 (2048,)
  const float* sinks  = (const float*)d_in[5];   // fp32 (32,)

  // ws layout (67.1 MB):
  //   [0, 25165824)            qkvb bf16 (4096 x 3072; v section unused)
  //   [25165824, 29360128)     vT bf16 [b][kv][64][1024]
  //   [29360128, 46137344)     x bf16, later aliased as attn bf16 out
  //   [46137344, 58720256)     qkv_w bf16
  //   [58720256, 67108864)     out_w bf16
  char* ws = (char*)d_ws;
  short* qkvb = (short*)ws;
  short* vT   = (short*)(ws + 25165824);
  short* xb   = (short*)(ws + 29360128);
  short* wqb  = (short*)(ws + 46137344);
  short* wob  = (short*)(ws + 58720256);
  short* attn = xb;                            // aliased: xb dead after gemm_qkv
  float* out  = (float*)d_out;

  cvt_kernel<<<18432, 256, 0, stream>>>(x, qkv_w, out_w, xb, wqb, wob);
  gemm_qkv<<<dim3(QKVD / 128, 4096 / 128), 256, 0, stream>>>(xb, wqb, qkv_b, qkvb, vT);
  attn_kernel<<<dim3(T_ / 32, 8, B_), 256, 0, stream>>>(qkvb, vT, sinks, attn);
  gemm_out<<<dim3(DM / 128, 4096 / 128), 256, 0, stream>>>(attn, wob, out_b, out);
}

// Round 7
// 262.981 us; speedup vs baseline: 1.0226x; 1.0226x over previous
//
#include <hip/hip_runtime.h>
#include <hip/hip_bf16.h>

#define B_   4
#define T_   1024
#define DM   2048
#define QKVD 3072   // 64*(32+16)

typedef __attribute__((ext_vector_type(8))) short bf16x8;
typedef __attribute__((ext_vector_type(4))) short short4v;
typedef __attribute__((ext_vector_type(4))) float f32x4;

__device__ __forceinline__ void load_lds16(const void* g, void* l) {
  __builtin_amdgcn_global_load_lds((const __attribute__((address_space(1))) void*)g,
                                   (__attribute__((address_space(3))) void*)l, 16, 0, 0);
}

__device__ __forceinline__ short f2bf(float f) {
  __hip_bfloat16 h = __float2bfloat16(f);
  return *reinterpret_cast<short*>(&h);
}

// Fused fp32 -> bf16 convert for x (8.4M), qkv_w (6.3M), out_w (4.2M).
__global__ __launch_bounds__(256) void cvt_kernel(const float* __restrict__ x,
                                                  const float* __restrict__ w1,
                                                  const float* __restrict__ w2,
                                                  short* __restrict__ xo,
                                                  short* __restrict__ w1o,
                                                  short* __restrict__ w2o) {
  unsigned c = blockIdx.x * 256u + threadIdx.x;  // 0 .. 4718591
  const float* src;
  short* dst;
  if (c < 2097152u) {                 // x
    src = x; dst = xo;
  } else if (c < 3670016u) {          // qkv_w
    c -= 2097152u; src = w1; dst = w1o;
  } else {                            // out_w
    c -= 3670016u; src = w2; dst = w2o;
  }
  const float4 v = ((const float4*)src)[c];
  short4v o;
  o.x = f2bf(v.x); o.y = f2bf(v.y); o.z = f2bf(v.z); o.w = f2bf(v.w);
  ((short4v*)dst)[c] = o;
}

// Shared GEMM K-loop: m97 structure, BK=32, 16 KB LDS (3 blocks/CU — BK=64's
// 32 KB LDS dropped occupancy to ~2 blocks/CU and regressed 70->79.5 µs,
// round 6), 2-bit XOR bank swizzle (LDS chunk (r,q') holds global chunk
// q'^((r>>1)&3): frag b128 reads spread 2-way over banks = free per m136;
// unswizzled was 6.29M conflict cycles, round 4).
#define GEMM_PROLOGUE_AND_KLOOP(A_, B_ptr, K_)                                     \
  __shared__ short As[128 * 32];                                                   \
  __shared__ short Bs[128 * 32];                                                   \
  const int tid  = threadIdx.x;                                                    \
  const int lane = tid & 63;                                                       \
  const int wave = tid >> 6;                                                       \
  const int wm = wave >> 1, wn = wave & 1;                                         \
  const int r15 = lane & 15, quad = lane >> 4;                                     \
  const int m0 = blockIdx.y * 128, n0 = blockIdx.x * 128;                          \
  f32x4 acc[4][4];                                                                 \
  _Pragma("unroll") for (int i = 0; i < 4; ++i)                                    \
    _Pragma("unroll") for (int j = 0; j < 4; ++j) acc[i][j] = {0.f,0.f,0.f,0.f};   \
  const int ca0 = tid, ca1 = tid + 256;                                            \
  const int sr0 = ca0 >> 2, sr1 = ca1 >> 2;                                        \
  const int sq0 = (ca0 & 3) ^ ((sr0 >> 1) & 3);                                    \
  const int sq1 = (ca1 & 3) ^ ((sr1 >> 1) & 3);                                    \
  const short* gA0 = A_ + (size_t)(m0 + sr0) * K_ + sq0 * 8;                       \
  const short* gA1 = A_ + (size_t)(m0 + sr1) * K_ + sq1 * 8;                       \
  const short* gB0 = B_ptr + (size_t)(n0 + sr0) * K_ + sq0 * 8;                    \
  const short* gB1 = B_ptr + (size_t)(n0 + sr1) * K_ + sq1 * 8;                    \
  short* lA0 = &As[ca0 * 8];                                                       \
  short* lA1 = &As[ca1 * 8];                                                       \
  short* lB0 = &Bs[ca0 * 8];                                                       \
  short* lB1 = &Bs[ca1 * 8];                                                       \
  const int sw = (r15 >> 1) & 3;                                                   \
  const int fo = (quad ^ sw) * 8;                                                  \
  for (int k0 = 0; k0 < K_; k0 += 32) {                                            \
    __syncthreads();                                                               \
    load_lds16(gA0, lA0);                                                          \
    load_lds16(gA1, lA1);                                                          \
    load_lds16(gB0, lB0);                                                          \
    load_lds16(gB1, lB1);                                                          \
    gA0 += 32; gA1 += 32; gB0 += 32; gB1 += 32;                                    \
    __syncthreads();                                                               \
    bf16x8 af[4], bfr[4];                                                          \
    _Pragma("unroll") for (int tm = 0; tm < 4; ++tm)                               \
      af[tm] = *(const bf16x8*)&As[(wm * 64 + tm * 16 + r15) * 32 + fo];           \
    _Pragma("unroll") for (int tn = 0; tn < 4; ++tn)                               \
      bfr[tn] = *(const bf16x8*)&Bs[(wn * 64 + tn * 16 + r15) * 32 + fo];          \
    _Pragma("unroll") for (int tm = 0; tm < 4; ++tm)                               \
      _Pragma("unroll") for (int tn = 0; tn < 4; ++tn)                             \
        acc[tm][tn] = __builtin_amdgcn_mfma_f32_16x16x32_bf16(af[tm], bfr[tn],     \
                                                              acc[tm][tn], 0, 0, 0);\
  }

// QKV projection with fused bias + YaRN RoPE + SM_SCALE; q/k -> bf16 qkvb,
// v -> bf16 vT[b][kv][d][t] (transposed for attention's PV B-frags).
__global__ __launch_bounds__(256) void gemm_qkv(const short* __restrict__ A,
                                                const short* __restrict__ Bw,
                                                const float* __restrict__ bias,
                                                short* __restrict__ qkvb,
                                                short* __restrict__ vT) {
  GEMM_PROLOGUE_AND_KLOOP(A, Bw, 2048)

  if (blockIdx.x < 20) {
    // q (cols<2048) or k (2048..2559): bias + rope (+0.125 scale for q)
    const float scale = (blockIdx.x < 16) ? 0.125f : 1.0f;
    float invf[2];
#pragma unroll
    for (int tnh = 0; tnh < 2; ++tnh) {
      const float fi = (float)(tnh * 16 + r15);   // i = col & 31
      const float freq = __powf(150000.f, fi * (1.f / 32.f));
      float ramp = (fi - 4.3707300f) * (1.f / 9.3052397f);
      ramp = fminf(fmaxf(ramp, 0.f), 1.f);
      invf[tnh] = ramp / (32.f * freq) + (1.f - ramp) / freq;
    }
    float bv[4];
#pragma unroll
    for (int tn = 0; tn < 4; ++tn) bv[tn] = bias[n0 + wn * 64 + tn * 16 + r15];
#pragma unroll
    for (int tm = 0; tm < 4; ++tm)
#pragma unroll
      for (int v = 0; v < 4; ++v) {
        const int row = m0 + wm * 64 + tm * 16 + quad * 4 + v;
        const float ft = (float)(row & 1023);       // per-batch position
#pragma unroll
        for (int tnh = 0; tnh < 2; ++tnh) {
          const float ph = ft * invf[tnh];
          const float c = __cosf(ph) * 1.3465736f;  // concentration = 0.1*ln(32)+1
          const float s = __sinf(ph) * 1.3465736f;
          const float x1 = acc[tm][tnh][v] + bv[tnh];
          const float x2 = acc[tm][tnh + 2][v] + bv[tnh + 2];
          short* qp = qkvb + (size_t)row * QKVD + (n0 + wn * 64 + tnh * 16 + r15);
          qp[0]  = f2bf((x1 * c - x2 * s) * scale);
          qp[32] = f2bf((x2 * c + x1 * s) * scale);
        }
      }
  } else {
    // v (cols 2560..3071): bias, write transposed vT[b][kv][d][t], short4 packs
#pragma unroll
    for (int tn = 0; tn < 4; ++tn) {
      const int col = n0 + wn * 64 + tn * 16 + r15;
      const float bvv = bias[col];
      const int d = col & 63;
      const int kvh = (col - 2560) >> 6;
#pragma unroll
      for (int tm = 0; tm < 4; ++tm) {
        const int row = m0 + wm * 64 + tm * 16 + quad * 4;
        const int bb = row >> 10, tt = row & 1023;
        short4v st;
        st.x = f2bf(acc[tm][tn][0] + bvv);
        st.y = f2bf(acc[tm][tn][1] + bvv);
        st.z = f2bf(acc[tm][tn][2] + bvv);
        st.w = f2bf(acc[tm][tn][3] + bvv);
        *(short4v*)&vT[(size_t)((bb * 8 + kvh) * 64 + d) * 1024 + tt] = st;
      }
    }
  }
}

// Output projection: C fp32 = A bf16 * B^T bf16 + bias
__global__ __launch_bounds__(256) void gemm_out(const short* __restrict__ A,
                                                const short* __restrict__ Bw,
                                                const float* __restrict__ bias,
                                                float* __restrict__ C) {
  GEMM_PROLOGUE_AND_KLOOP(A, Bw, 2048)
#pragma unroll
  for (int tn = 0; tn < 4; ++tn) {
    const int col = n0 + wn * 64 + tn * 16 + r15;
    const float bv = bias[col];
#pragma unroll
    for (int tm = 0; tm < 4; ++tm) {
      const int row = m0 + wm * 64 + tm * 16 + quad * 4;
#pragma unroll
      for (int v = 0; v < 4; ++v)
        C[(size_t)(row + v) * DM + col] = acc[tm][tn][v] + bv;
    }
  }
}

// MFMA flash-style sliding-window attention, all-bf16 inputs.
// Block = (b, kv, 32-query tile), 4 waves = 4 GQA sub-heads, 4 blocks/CU.
// K/V staged via global_load_lds (16B) into unpadded 64-stride LDS with a
// 3-bit XOR swizzle (2-way banks = free). P per-wave in LDS padded to
// stride 72 (VALU-written). Fixed m=0 softmax (exact: shift-invariant,
// scores bounded well below exp overflow).
#define LSTR 72
__global__ __launch_bounds__(256, 4) void attn_kernel(const short* __restrict__ qkvb,
                                                      const short* __restrict__ vT,
                                                      const float* __restrict__ sinks,
                                                      short* __restrict__ attn_out) {
  __shared__ short Kb[64 * 64];        // [key][dim], swizzled chunks
  __shared__ short Vt[64 * 64];        // [dim][key], swizzled chunks
  __shared__ short Pl[4][32 * LSTR];   // per-wave [query][key]
  const int tid  = threadIdx.x;
  const int lane = tid & 63;
  const int m    = tid >> 6;
  const int r15  = lane & 15, quad = lane >> 4;
  const int t0 = blockIdx.x * 32;
  const int kv = blockIdx.y;
  const int b  = blockIdx.z;
  const int swf = r15 & 7;

  bf16x8 qf[2][2];
#pragma unroll
  for (int tm = 0; tm < 2; ++tm)
#pragma unroll
    for (int kc = 0; kc < 2; ++kc)
      qf[tm][kc] = *(const bf16x8*)&qkvb[(size_t)(b * T_ + t0 + tm * 16 + r15) * QKVD
                                         + kv * 256 + m * 64 + kc * 32 + quad * 8];

  f32x4 oacc[2][4];
#pragma unroll
  for (int i = 0; i < 2; ++i)
#pragma unroll
    for (int j = 0; j < 4; ++j) oacc[i][j] = {0.f, 0.f, 0.f, 0.f};
  float lf[8];
#pragma unroll
  for (int i = 0; i < 8; ++i) lf[i] = 0.f;

  const short* kbase = qkvb + (size_t)b * T_ * QKVD + 2048 + kv * 64;
  const short* vbase = vT + (size_t)((b * 8 + kv) * 64) * 1024;

  // 64-aligned key tiles covering [max(0, t0-127), t0+31]
  const int jt_lo = (t0 >= 127) ? ((t0 - 127) >> 6) : 0;
  const int jt_hi = (t0 + 31) >> 6;

  for (int jt = jt_lo; jt <= jt_hi; ++jt) {
    const int j0 = jt * 64;
    __syncthreads();  // previous tile fully consumed
#pragma unroll
    for (int i = 0; i < 2; ++i) {
      const int c = i * 256 + tid;
      const int r = c >> 3, qs = (c & 7) ^ (r & 7);
      load_lds16(kbase + (size_t)(j0 + r) * QKVD + qs * 8, &Kb[c * 8]);
      load_lds16(vbase + (size_t)r * 1024 + j0 + qs * 8, &Vt[c * 8]);
    }
    __syncthreads();  // vmcnt(0) drain -> LDS ready

    // S = Q K^T : C/D layout col(key)=tn*16+r15, row(query)=tm*16+quad*4+v
    f32x4 sacc[2][4];
#pragma unroll
    for (int i = 0; i < 2; ++i)
#pragma unroll
      for (int j = 0; j < 4; ++j) sacc[i][j] = {0.f, 0.f, 0.f, 0.f};
#pragma unroll
    for (int kc = 0; kc < 2; ++kc) {
      bf16x8 bk[4];
#pragma unroll
      for (int tn = 0; tn < 4; ++tn)
        bk[tn] = *(const bf16x8*)&Kb[(tn * 16 + r15) * 64 + ((kc * 4 + quad) ^ swf) * 8];
#pragma unroll
      for (int tm = 0; tm < 2; ++tm)
#pragma unroll
        for (int tn = 0; tn < 4; ++tn)
          sacc[tm][tn] = __builtin_amdgcn_mfma_f32_16x16x32_bf16(qf[tm][kc], bk[tn],
                                                                 sacc[tm][tn], 0, 0, 0);
    }

    // mask + exp + row-sum partials + P to per-wave LDS
    short* pl = &Pl[m][0];
#pragma unroll
    for (int tm = 0; tm < 2; ++tm)
#pragma unroll
      for (int v = 0; v < 4; ++v) {
        const int ql = tm * 16 + quad * 4 + v;
        const int t = t0 + ql;
        float lsum = 0.f;
#pragma unroll
        for (int tn = 0; tn < 4; ++tn) {
          const int j = j0 + tn * 16 + r15;
          const bool valid = (unsigned)(t - j) <= 127u;
          const float e = valid ? __expf(sacc[tm][tn][v]) : 0.f;
          lsum += e;
          pl[ql * LSTR + tn * 16 + r15] = f2bf(e);
        }
        lf[tm * 4 + v] += lsum;
      }

    // O += P V (A from Pl, B from Vt; same-wave RAW via lgkmcnt)
#pragma unroll
    for (int kc = 0; kc < 2; ++kc) {
      bf16x8 ap[2], bv[4];
#pragma unroll
      for (int tm = 0; tm < 2; ++tm)
        ap[tm] = *(const bf16x8*)&pl[(tm * 16 + r15) * LSTR + kc * 32 + quad * 8];
#pragma unroll
      for (int tn = 0; tn < 4; ++tn)
        bv[tn] = *(const bf16x8*)&Vt[(tn * 16 + r15) * 64 + ((kc * 4 + quad) ^ swf) * 8];
#pragma unroll
      for (int tm = 0; tm < 2; ++tm)
#pragma unroll
        for (int tn = 0; tn < 4; ++tn)
          oacc[tm][tn] = __builtin_amdgcn_mfma_f32_16x16x32_bf16(ap[tm], bv[tn],
                                                                 oacc[tm][tn], 0, 0, 0);
    }
  }

  // reduce l over the 16-lane r15 group, fold sink, normalize, store bf16
#pragma unroll
  for (int i = 0; i < 8; ++i) {
    float v = lf[i];
    v += __shfl_xor(v, 1, 64);
    v += __shfl_xor(v, 2, 64);
    v += __shfl_xor(v, 4, 64);
    v += __shfl_xor(v, 8, 64);
    lf[i] = v;
  }
  const int h = kv * 4 + m;
  const float snk = __expf(sinks[h]);
#pragma unroll
  for (int tm = 0; tm < 2; ++tm)
#pragma unroll
    for (int v = 0; v < 4; ++v) {
      const float inv = 1.f / (lf[tm * 4 + v] + snk);
      const int t = t0 + tm * 16 + quad * 4 + v;
      short* op = attn_out + (size_t)(b * T_ + t) * DM + h * 64;
#pragma unroll
      for (int tn = 0; tn < 4; ++tn)
        op[tn * 16 + r15] = f2bf(oacc[tm][tn][v] * inv);
    }
}

extern "C" void kernel_launch(void* const* d_in, const int* in_sizes, int n_in,
                              void* d_out, int out_size, void* d_ws, size_t ws_size,
                              hipStream_t stream) {
  const float* x      = (const float*)d_in[0];   // fp32 (B,T,DM)
  const float* qkv_w  = (const float*)d_in[1];   // fp32 (3072,2048)
  const float* qkv_b  = (const float*)d_in[2];   // fp32 (3072,)
  const float* out_w  = (const float*)d_in[3];   // fp32 (2048,2048)
  const float* out_b  = (const float*)d_in[4];   // fp32 (2048,)
  const float* sinks  = (const float*)d_in[5];   // fp32 (32,)

  // ws layout (67.1 MB):
  //   [0, 25165824)            qkvb bf16 (4096 x 3072; v section unused)
  //   [25165824, 29360128)     vT bf16 [b][kv][64][1024]
  //   [29360128, 46137344)     x bf16, later aliased as attn bf16 out
  //   [46137344, 58720256)     qkv_w bf16
  //   [58720256, 67108864)     out_w bf16
  char* ws = (char*)d_ws;
  short* qkvb = (short*)ws;
  short* vT   = (short*)(ws + 25165824);
  short* xb   = (short*)(ws + 29360128);
  short* wqb  = (short*)(ws + 46137344);
  short* wob  = (short*)(ws + 58720256);
  short* attn = xb;                            // aliased: xb dead after gemm_qkv
  float* out  = (float*)d_out;

  cvt_kernel<<<18432, 256, 0, stream>>>(x, qkv_w, out_w, xb, wqb, wob);
  gemm_qkv<<<dim3(QKVD / 128, 4096 / 128), 256, 0, stream>>>(xb, wqb, qkv_b, qkvb, vT);
  attn_kernel<<<dim3(T_ / 32, 8, B_), 256, 0, stream>>>(qkvb, vT, sinks, attn);
  gemm_out<<<dim3(DM / 128, 4096 / 128), 256, 0, stream>>>(attn, wob, out_b, out);
}